// Round 4
// baseline (256.731 us; speedup 1.0000x reference)
//
#include <hip/hip_runtime.h>
#include <cstdint>
#include <cstddef>

// ---- problem constants ----
#define SEQ   920
#define DM    1536
#define DH    384
#define NHD   4
#define NB    4
#define NBH   16          // NB*NHD
#define MTOK  3680        // NB*SEQ
#define NREL  1839        // 2*920-1

typedef short          bf16x8 __attribute__((ext_vector_type(8)));
typedef float          f32x4  __attribute__((ext_vector_type(4)));
typedef unsigned short u16x4  __attribute__((ext_vector_type(4)));

__device__ __forceinline__ unsigned short f2bf(float f){
  union{float f; unsigned u;} v; v.f = f;
  unsigned r = v.u + 0x7FFFu + ((v.u >> 16) & 1u);
  return (unsigned short)(r >> 16);
}
__device__ __forceinline__ float bf2f(unsigned short h){
  union{unsigned u; float f;} v; v.u = ((unsigned)h) << 16;
  return v.f;
}
__device__ __forceinline__ f32x4 mfma_bf16(bf16x8 a, bf16x8 b, f32x4 c){
  return __builtin_amdgcn_mfma_f32_16x16x32_bf16(a, b, c, 0, 0, 0);
}
__device__ __forceinline__ void gload_lds16(const void* g, void* l){
  __builtin_amdgcn_global_load_lds((const __attribute__((address_space(1))) void*)g,
                                   (__attribute__((address_space(3))) void*)l, 16, 0, 0);
}

// ---------------- convert f32 -> bf16 (n % 4 == 0) ----------------
__global__ __launch_bounds__(256) void k_f2bf(const float* __restrict__ src,
                                              unsigned short* __restrict__ dst, int n){
  int i = (blockIdx.x * 256 + threadIdx.x) * 4;
  int stride = gridDim.x * 256 * 4;
  for(; i + 3 < n; i += stride){
    f32x4 v = *(const f32x4*)(src + i);
    u16x4 o; o.x = f2bf(v.x); o.y = f2bf(v.y); o.z = f2bf(v.z); o.w = f2bf(v.w);
    *(u16x4*)(dst + i) = o;
  }
}

// ---- transpose+convert all 3 weights: W[k][n] f32 -> Wt[z*1536+n][k] bf16 (z = blockIdx.z) ----
__global__ __launch_bounds__(256) void k_wt3(const float* __restrict__ qw,
                                             const float* __restrict__ kw,
                                             const float* __restrict__ vw,
                                             unsigned short* __restrict__ wt){
  __shared__ float t[32][33];
  const float* w = blockIdx.z == 0 ? qw : (blockIdx.z == 1 ? kw : vw);
  int k0 = blockIdx.x * 32, n0 = blockIdx.y * 32;
  int tx = threadIdx.x, ty = threadIdx.y;       // (32,8)
  #pragma unroll
  for(int j = 0; j < 4; j++)
    t[ty*4+j][tx] = w[(size_t)(k0 + ty*4 + j) * DM + n0 + tx];
  __syncthreads();
  #pragma unroll
  for(int j = 0; j < 4; j++)
    wt[(size_t)(blockIdx.z*DM + n0 + ty*4 + j) * DM + k0 + tx] = f2bf(t[tx][ty*4+j]);
}

// ================= 192x192 tile, BK=64, 8-wave, ring-3 counted-vmcnt GEMM =================
template<class Epi>
__device__ __forceinline__ void gemm192(const unsigned short* __restrict__ A, int lda, int Amax,
                                        const unsigned short* __restrict__ B, int ldb, int Bmax,
                                        int K, int m0, int n0, Epi epi){
  __shared__ unsigned short As[3*192*64];   // 3 slots x 24KB, rows 128B, XOR-swizzled content
  __shared__ unsigned short Bs[3*192*64];
  const int tid = threadIdx.x;
  const int w = tid >> 6, l = tid & 63;
  const int lg = l >> 4, lo = l & 15;
  const int wm = w >> 2, wn = w & 3;        // wave grid 2(M) x 4(N); per-wave 96x48

  const char* ga[3]; const char* gb[3];
  #pragma unroll
  for(int r = 0; r < 3; r++){
    int row = r*64 + (tid >> 3);
    int gslot = (tid & 7) ^ (row & 7);
    int ar = m0 + row; ar = ar < Amax ? ar : Amax - 1;
    ga[r] = (const char*)A + (size_t)ar*lda*2 + gslot*16;
    int br = n0 + row; br = br < Bmax ? br : Bmax - 1;
    gb[r] = (const char*)B + (size_t)br*ldb*2 + gslot*16;
  }
  const int ldst = tid * 16;

  auto stage = [&](int kt, int slot){
    size_t koff = (size_t)kt * 128;         // 64 cols * 2B
    #pragma unroll
    for(int r = 0; r < 3; r++){
      gload_lds16(ga[r] + koff, (char*)As + slot*24576 + r*8192 + ldst);
      gload_lds16(gb[r] + koff, (char*)Bs + slot*24576 + r*8192 + ldst);
    }
  };

  f32x4 acc[6][3] = {};
  const int sw = (lo & 7) << 4;

  auto compute = [&](int slot){
    const char* Ab = (const char*)As + slot*24576;
    const char* Bb = (const char*)Bs + slot*24576;
    bf16x8 af[6][2], bf[3][2];
    #pragma unroll
    for(int fi = 0; fi < 6; fi++){
      int row = wm*96 + fi*16 + lo;
      #pragma unroll
      for(int kk = 0; kk < 2; kk++)
        af[fi][kk] = *(const bf16x8*)(Ab + row*128 + ((kk*64 + lg*16) ^ sw));
    }
    #pragma unroll
    for(int fj = 0; fj < 3; fj++){
      int row = wn*48 + fj*16 + lo;
      #pragma unroll
      for(int kk = 0; kk < 2; kk++)
        bf[fj][kk] = *(const bf16x8*)(Bb + row*128 + ((kk*64 + lg*16) ^ sw));
    }
    __builtin_amdgcn_s_setprio(1);
    #pragma unroll
    for(int kk = 0; kk < 2; kk++)
      #pragma unroll
      for(int fi = 0; fi < 6; fi++)
        #pragma unroll
        for(int fj = 0; fj < 3; fj++)
          acc[fi][fj] = mfma_bf16(af[fi][kk], bf[fj][kk], acc[fi][fj]);
    __builtin_amdgcn_s_setprio(0);
  };

  const int nk = K >> 6;
  stage(0, 0);
  stage(1, 1);
  int st = 0;
  for(int t = 0; t < nk; t++){
    if(t + 2 < nk){
      int s2 = st + 2 >= 3 ? st - 1 : st + 2;
      stage(t + 2, s2);
      asm volatile("s_waitcnt vmcnt(12)" ::: "memory");  // tiles t+1,t+2 still in flight
    } else if(t + 1 < nk){
      asm volatile("s_waitcnt vmcnt(6)" ::: "memory");
    } else {
      asm volatile("s_waitcnt vmcnt(0)" ::: "memory");
    }
    __builtin_amdgcn_s_barrier();
    compute(st);
    __builtin_amdgcn_s_barrier();
    st = st + 1 >= 3 ? 0 : st + 1;
  }

  #pragma unroll
  for(int fi = 0; fi < 6; fi++)
    #pragma unroll
    for(int fj = 0; fj < 3; fj++){
      int m = m0 + wm*96 + fi*16 + lg*4;
      int n = n0 + wn*48 + fj*16 + lo;
      epi(m, n, acc[fi][fj]);
    }
}

// ---------------- projection: C = X @ [qw kw vw] -> Qb/Kb (bh,s,d), Vt (bh,d,s) ----------------
__global__ __launch_bounds__(512) void k_proj(const unsigned short* __restrict__ X,
                                              const unsigned short* __restrict__ Wt,
                                              unsigned short* __restrict__ Qb,
                                              unsigned short* __restrict__ Kb,
                                              unsigned short* __restrict__ Vt){
  int bid = blockIdx.x;                       // 480 blocks, 480 % 8 == 0
  int wg  = (bid & 7) * 60 + (bid >> 3);      // XCD-contiguous chunks
  int m0 = (wg % 20) * 192, n0 = (wg / 20) * 192;
  gemm192(X, DM, MTOK, Wt, DM, 3*DM, DM, m0, n0,
    [=] __device__ (int m, int n, f32x4 v4){
      if(m >= MTOK) return;                   // 4-row group fully in/out (both %4==0)
      int which = n / DM, r = n % DM, h = r / DH, d = r % DH;
      int b = m / SEQ, s = m % SEQ;           // 920%4==0 -> group stays in one b
      int bh = b * NHD + h;
      if(which == 2){
        u16x4 o;
        o.x = f2bf(v4.x); o.y = f2bf(v4.y); o.z = f2bf(v4.z); o.w = f2bf(v4.w);
        *(u16x4*)(Vt + ((size_t)bh*DH + d)*SEQ + s) = o;
      } else if(which == 0){
        #pragma unroll
        for(int i = 0; i < 4; i++)
          Qb[((size_t)bh*SEQ + s + i)*DH + d] = f2bf(v4[i] * 0.05103103630798287f);
      } else {
        #pragma unroll
        for(int i = 0; i < 4; i++)
          Kb[((size_t)bh*SEQ + s + i)*DH + d] = f2bf(v4[i]);
      }
    });
}

// ---------------- rel: C = Q_all @ E^T, banded epilogue -> relS[bh*920+q][k] ----------------
__global__ __launch_bounds__(512) void k_rel(const unsigned short* __restrict__ Qb,
                                             const unsigned short* __restrict__ E,
                                             unsigned short* __restrict__ relS){
  int m0 = blockIdx.x * 192, n0 = blockIdx.y * 192;
  int s0 = m0 % SEQ;
  int qlo = s0, qhi = s0 + 191;
  if(qhi >= SEQ){ qlo = 0; qhi = SEQ - 1; }
  if(n0 + 191 < 919 - qhi || n0 > 1838 - qlo) return;
  gemm192(Qb, DH, NBH*SEQ, E, DH, NREL, DH, m0, n0,
    [=] __device__ (int m, int n, f32x4 v4){
      #pragma unroll
      for(int i = 0; i < 4; i++){
        int mi = m + i;
        if(mi >= NBH*SEQ) continue;
        int q = mi % SEQ;
        int j = n - 919 + q;
        if(j < 0 || j >= SEQ) continue;
        relS[(size_t)mi*SEQ + j] = f2bf(v4[i]);
      }
    });
}

// ---------------- fused attention: no K/V LDS staging (L2-resident), KVBLK=64 ----------------
__global__ __launch_bounds__(256) void k_attn(const unsigned short* __restrict__ Qb,
                                              const unsigned short* __restrict__ Kb,
                                              const unsigned short* __restrict__ Vt,
                                              const unsigned short* __restrict__ relS,
                                              float* __restrict__ out){
  __shared__ unsigned short Pl[32*72];    // P tile 32x64, rows 144B (2-way bank alias = free)
  __shared__ float sums[2][32];
  const int bh = blockIdx.y, q0 = blockIdx.x * 32;
  const int tid = threadIdx.x, w = tid >> 6, l = tid & 63;
  const int mi = w >> 1, ni = w & 1;
  const int lg = l >> 4, lo = l & 15;

  // hoist Q A-frags (lane lo = q-row, lg = k-quarter)
  int qrow = q0 + mi*16 + lo; if(qrow > SEQ-1) qrow = SEQ-1;
  const char* Qrow = (const char*)(Qb + ((size_t)bh*SEQ + qrow)*DH);
  bf16x8 qf[12];
  #pragma unroll
  for(int ks = 0; ks < 12; ks++) qf[ks] = *(const bf16x8*)(Qrow + ks*64 + lg*16);

  const char* Kbh = (const char*)(Kb + (size_t)bh*SEQ*DH);
  const char* Vbh = (const char*)(Vt + (size_t)bh*DH*SEQ);
  const unsigned short* Rbh = relS + (size_t)bh*SEQ*SEQ;

  f32x4 ctx[2][6] = {};
  float ps[4] = {0.f, 0.f, 0.f, 0.f};

  for(int kt = 0; kt < 15; kt++){
    const int k0 = kt * 64;
    // ---- S = Q K^T : per wave 2 frags (k-cols ni*32 .. ni*32+31), B-frags direct from L2 ----
    f32x4 sacc[2] = {};
    #pragma unroll
    for(int f = 0; f < 2; f++){
      int krow = k0 + ni*32 + f*16 + lo; if(krow > SEQ-1) krow = SEQ-1;
      const char* Kr = Kbh + (size_t)krow*768;
      #pragma unroll
      for(int ks = 0; ks < 12; ks++){
        bf16x8 kb = *(const bf16x8*)(Kr + ks*64 + lg*16);
        sacc[f] = mfma_bf16(qf[ks], kb, sacc[f]);
      }
    }
    // ---- + rel, exp (no max-sub), rowsums, stage P ----
    #pragma unroll
    for(int f = 0; f < 2; f++){
      #pragma unroll
      for(int i = 0; i < 4; i++){
        int q = q0 + mi*16 + lg*4 + i; if(q > SEQ-1) q = SEQ-1;
        int k = k0 + ni*32 + f*16 + lo;
        int kc = k > SEQ-1 ? SEQ-1 : k;
        float rl = bf2f(Rbh[(size_t)q*SEQ + kc]);
        float p = __expf(sacc[f][i] + rl);
        if(k >= SEQ) p = 0.f;
        ps[i] += p;
        *(unsigned short*)((char*)Pl + (mi*16 + lg*4 + i)*144 + (ni*32 + f*16 + lo)*2) = f2bf(p);
      }
    }
    __syncthreads();
    // ---- PV : A-frags from Pl, B-frags (V^T rows) direct from L2 ----
    bf16x8 pa[2][2];
    #pragma unroll
    for(int m2 = 0; m2 < 2; m2++)
      #pragma unroll
      for(int ksl = 0; ksl < 2; ksl++)
        pa[m2][ksl] = *(const bf16x8*)((char*)Pl + (m2*16 + lo)*144 + ksl*64 + lg*16);
    #pragma unroll
    for(int nj = 0; nj < 6; nj++){
      int d = w*96 + nj*16 + lo;
      const char* Vr = Vbh + (size_t)d*1840;
      #pragma unroll
      for(int ksl = 0; ksl < 2; ksl++){
        int ob = k0*2 + ksl*64 + lg*16; if(ob > 1824) ob = 1824;  // clamp: finite data, P=0 there
        bf16x8 vb = *(const bf16x8*)(Vr + ob);
        ctx[0][nj] = mfma_bf16(pa[0][ksl], vb, ctx[0][nj]);
        ctx[1][nj] = mfma_bf16(pa[1][ksl], vb, ctx[1][nj]);
      }
    }
    __syncthreads();
  }
  // row sums: reduce over the 16 lanes of each lg group, combine ni halves via LDS
  #pragma unroll
  for(int i = 0; i < 4; i++){
    float v = ps[i];
    v += __shfl_xor(v, 1); v += __shfl_xor(v, 2);
    v += __shfl_xor(v, 4); v += __shfl_xor(v, 8);
    if(lo == 0) sums[ni][mi*16 + lg*4 + i] = v;
  }
  __syncthreads();
  const int b = bh >> 2, h = bh & 3;
  #pragma unroll
  for(int m2 = 0; m2 < 2; m2++){
    #pragma unroll
    for(int i = 0; i < 4; i++){
      int ql = m2*16 + lg*4 + i;
      int q = q0 + ql;
      if(q >= SEQ) continue;
      float inv = 1.0f / (sums[0][ql] + sums[1][ql]);
      #pragma unroll
      for(int nj = 0; nj < 6; nj++){
        int d = w*96 + nj*16 + lo;
        out[((size_t)(b*SEQ + q))*DM + h*DH + d] = ctx[m2][nj][i] * inv;
      }
    }
  }
}

extern "C" void kernel_launch(void* const* d_in, const int* in_sizes, int n_in,
                              void* d_out, int out_size, void* d_ws, size_t ws_size,
                              hipStream_t stream){
  const float* X  = (const float*)d_in[0];
  const float* qw = (const float*)d_in[1];
  const float* kw = (const float*)d_in[2];
  const float* vw = (const float*)d_in[3];
  const float* de = (const float*)d_in[4];
  float* out = (float*)d_out;
  char* ws = (char*)d_ws;

  unsigned short* Qb   = (unsigned short*)ws;
  unsigned short* Kb   = (unsigned short*)(ws + 11304960);
  unsigned short* Vt   = (unsigned short*)(ws + 22609920);
  unsigned short* Eb   = (unsigned short*)(ws + 33914880);
  char* regionR        = ws + 35327232;
  unsigned short* relS = (unsigned short*)regionR;
  unsigned short* Xb   = (unsigned short*)regionR;
  unsigned short* Wt   = (unsigned short*)(regionR + 11304960);

  k_f2bf<<<dim3(2048), dim3(256), 0, stream>>>(X,  Xb, MTOK*DM);
  k_f2bf<<<dim3(690),  dim3(256), 0, stream>>>(de, Eb, NREL*DH);
  k_wt3<<<dim3(48,48,3), dim3(32,8), 0, stream>>>(qw, kw, vw, Wt);
  k_proj<<<dim3(480), dim3(512), 0, stream>>>(Xb, Wt, Qb, Kb, Vt);
  k_rel<<<dim3(77,10), dim3(512), 0, stream>>>(Qb, Eb, relS);   // overwrites Xb/Wt (dead)
  k_attn<<<dim3(29,16), dim3(256), 0, stream>>>(Qb, Kb, Vt, relS, out);
}

// Round 5
// 230.927 us; speedup vs baseline: 1.1117x; 1.1117x over previous
//
#include <hip/hip_runtime.h>
#include <cstdint>
#include <cstddef>

// ---- problem constants ----
#define SEQ   920
#define DM    1536
#define DH    384
#define NHD   4
#define NB    4
#define NBH   16          // NB*NHD
#define MTOK  3680        // NB*SEQ
#define NREL  1839        // 2*920-1

typedef short          bf16x8 __attribute__((ext_vector_type(8)));
typedef float          f32x4  __attribute__((ext_vector_type(4)));
typedef unsigned short u16x4  __attribute__((ext_vector_type(4)));
typedef unsigned short u16x8  __attribute__((ext_vector_type(8)));

__device__ __forceinline__ unsigned short f2bf(float f){
  union{float f; unsigned u;} v; v.f = f;
  unsigned r = v.u + 0x7FFFu + ((v.u >> 16) & 1u);
  return (unsigned short)(r >> 16);
}
__device__ __forceinline__ float bf2f(unsigned short h){
  union{unsigned u; float f;} v; v.u = ((unsigned)h) << 16;
  return v.f;
}
__device__ __forceinline__ f32x4 mfma_bf16(bf16x8 a, bf16x8 b, f32x4 c){
  return __builtin_amdgcn_mfma_f32_16x16x32_bf16(a, b, c, 0, 0, 0);
}
__device__ __forceinline__ void gload_lds16(const void* g, void* l){
  __builtin_amdgcn_global_load_lds((const __attribute__((address_space(1))) void*)g,
                                   (__attribute__((address_space(3))) void*)l, 16, 0, 0);
}

// ---------------- convert f32 -> bf16 (n % 4 == 0) ----------------
__global__ __launch_bounds__(256) void k_f2bf(const float* __restrict__ src,
                                              unsigned short* __restrict__ dst, int n){
  int i = (blockIdx.x * 256 + threadIdx.x) * 4;
  int stride = gridDim.x * 256 * 4;
  for(; i + 3 < n; i += stride){
    f32x4 v = *(const f32x4*)(src + i);
    u16x4 o; o.x = f2bf(v.x); o.y = f2bf(v.y); o.z = f2bf(v.z); o.w = f2bf(v.w);
    *(u16x4*)(dst + i) = o;
  }
}

// ---- transpose+convert all 3 weights: W[k][n] f32 -> Wt[z*1536+n][k] bf16 (z = blockIdx.z) ----
__global__ __launch_bounds__(256) void k_wt3(const float* __restrict__ qw,
                                             const float* __restrict__ kw,
                                             const float* __restrict__ vw,
                                             unsigned short* __restrict__ wt){
  __shared__ float t[32][33];
  const float* w = blockIdx.z == 0 ? qw : (blockIdx.z == 1 ? kw : vw);
  int k0 = blockIdx.x * 32, n0 = blockIdx.y * 32;
  int tx = threadIdx.x, ty = threadIdx.y;       // (32,8)
  #pragma unroll
  for(int j = 0; j < 4; j++)
    t[ty*4+j][tx] = w[(size_t)(k0 + ty*4 + j) * DM + n0 + tx];
  __syncthreads();
  #pragma unroll
  for(int j = 0; j < 4; j++)
    wt[(size_t)(blockIdx.z*DM + n0 + ty*4 + j) * DM + k0 + tx] = f2bf(t[tx][ty*4+j]);
}

// ================= 192x192 tile, BK=64, 8-wave, ring-3 counted-vmcnt GEMM =================
// B given as B^T (n-major, ldb = K elements). K need NOT be a multiple of 64: the last
// 128B k-chunk is masked on the A side in registers (valid bytes tb = 2K - (nk-1)*128,
// 16B granularity), so B-side garbage from row overreads multiplies zero. Row overreads
// (up to 80B past the last staged row) must land in mapped memory — layout guarantees this.
template<class Epi>
__device__ __forceinline__ void gemm192(const unsigned short* __restrict__ A, int lda, int Amax,
                                        const unsigned short* __restrict__ B, int ldb, int Bmax,
                                        int K, int m0, int n0, Epi epi){
  __shared__ unsigned short As[3*192*64];   // 3 slots x 24KB, rows 128B, XOR-swizzled content
  __shared__ unsigned short Bs[3*192*64];
  const int tid = threadIdx.x;
  const int w = tid >> 6, l = tid & 63;
  const int lg = l >> 4, lo = l & 15;
  const int wm = w >> 2, wn = w & 3;        // wave grid 2(M) x 4(N); per-wave 96x48

  const char* ga[3]; const char* gb[3];
  #pragma unroll
  for(int r = 0; r < 3; r++){
    int row = r*64 + (tid >> 3);
    int gslot = (tid & 7) ^ (row & 7);
    int ar = m0 + row; ar = ar < Amax ? ar : Amax - 1;
    ga[r] = (const char*)A + (size_t)ar*lda*2 + gslot*16;
    int br = n0 + row; br = br < Bmax ? br : Bmax - 1;
    gb[r] = (const char*)B + (size_t)br*ldb*2 + gslot*16;
  }
  const int ldst = tid * 16;

  auto stage = [&](int kt, int slot){
    size_t koff = (size_t)kt * 128;         // 64 cols * 2B
    #pragma unroll
    for(int r = 0; r < 3; r++){
      gload_lds16(ga[r] + koff, (char*)As + slot*24576 + r*8192 + ldst);
      gload_lds16(gb[r] + koff, (char*)Bs + slot*24576 + r*8192 + ldst);
    }
  };

  f32x4 acc[6][3] = {};
  const int sw = (lo & 7) << 4;
  const int nk = (2*K + 127) >> 7;
  const int tb = 2*K - (nk - 1)*128;        // valid bytes in last k-chunk (128 if K%64==0)
  const bool keep0 = (lg*16) < tb;          // kk=0 sub-chunk
  const bool keep1 = (64 + lg*16) < tb;     // kk=1 sub-chunk

  auto compute = [&](int slot, bool last){
    const char* Ab = (const char*)As + slot*24576;
    const char* Bb = (const char*)Bs + slot*24576;
    bf16x8 af[6][2], bf[3][2];
    #pragma unroll
    for(int fi = 0; fi < 6; fi++){
      int row = wm*96 + fi*16 + lo;
      #pragma unroll
      for(int kk = 0; kk < 2; kk++)
        af[fi][kk] = *(const bf16x8*)(Ab + row*128 + ((kk*64 + lg*16) ^ sw));
    }
    #pragma unroll
    for(int fj = 0; fj < 3; fj++){
      int row = wn*48 + fj*16 + lo;
      #pragma unroll
      for(int kk = 0; kk < 2; kk++)
        bf[fj][kk] = *(const bf16x8*)(Bb + row*128 + ((kk*64 + lg*16) ^ sw));
    }
    if(last){
      #pragma unroll
      for(int fi = 0; fi < 6; fi++){
        if(!keep0) af[fi][0] = bf16x8{};
        if(!keep1) af[fi][1] = bf16x8{};
      }
    }
    __builtin_amdgcn_s_setprio(1);
    #pragma unroll
    for(int kk = 0; kk < 2; kk++)
      #pragma unroll
      for(int fi = 0; fi < 6; fi++)
        #pragma unroll
        for(int fj = 0; fj < 3; fj++)
          acc[fi][fj] = mfma_bf16(af[fi][kk], bf[fj][kk], acc[fi][fj]);
    __builtin_amdgcn_s_setprio(0);
  };

  stage(0, 0);
  stage(1, 1);
  int st = 0;
  for(int t = 0; t < nk; t++){
    if(t + 2 < nk){
      int s2 = st + 2 >= 3 ? st - 1 : st + 2;
      stage(t + 2, s2);
      asm volatile("s_waitcnt vmcnt(12)" ::: "memory");  // tiles t+1,t+2 still in flight
    } else if(t + 1 < nk){
      asm volatile("s_waitcnt vmcnt(6)" ::: "memory");
    } else {
      asm volatile("s_waitcnt vmcnt(0)" ::: "memory");
    }
    __builtin_amdgcn_s_barrier();
    compute(st, t == nk - 1);
    __builtin_amdgcn_s_barrier();
    st = st + 1 >= 3 ? 0 : st + 1;
  }

  #pragma unroll
  for(int fi = 0; fi < 6; fi++)
    #pragma unroll
    for(int fj = 0; fj < 3; fj++){
      int m = m0 + wm*96 + fi*16 + lg*4;
      int n = n0 + wn*48 + fj*16 + lo;
      epi(m, n, acc[fi][fj]);
    }
}

// ---------------- projection: C = X @ [qw kw vw] -> Qb/Kb (bh,s,d), Vt (bh,d,s) ----------------
__global__ __launch_bounds__(512) void k_proj(const unsigned short* __restrict__ X,
                                              const unsigned short* __restrict__ Wt,
                                              unsigned short* __restrict__ Qb,
                                              unsigned short* __restrict__ Kb,
                                              unsigned short* __restrict__ Vt){
  int bid = blockIdx.x;                       // 480 blocks, 480 % 8 == 0
  int wg  = (bid & 7) * 60 + (bid >> 3);      // XCD-contiguous chunks
  int m0 = (wg % 20) * 192, n0 = (wg / 20) * 192;
  gemm192(X, DM, MTOK, Wt, DM, 3*DM, DM, m0, n0,
    [=] __device__ (int m, int n, f32x4 v4){
      if(m >= MTOK) return;                   // 4-row group fully in/out (both %4==0)
      int which = n / DM, r = n % DM, h = r / DH, d = r % DH;
      int b = m / SEQ, s = m % SEQ;           // 920%4==0 -> group stays in one b
      int bh = b * NHD + h;
      if(which == 2){
        u16x4 o;
        o.x = f2bf(v4.x); o.y = f2bf(v4.y); o.z = f2bf(v4.z); o.w = f2bf(v4.w);
        *(u16x4*)(Vt + ((size_t)bh*DH + d)*SEQ + s) = o;
      } else if(which == 0){
        #pragma unroll
        for(int i = 0; i < 4; i++)
          Qb[((size_t)bh*SEQ + s + i)*DH + d] = f2bf(v4[i] * 0.05103103630798287f);
      } else {
        #pragma unroll
        for(int i = 0; i < 4; i++)
          Kb[((size_t)bh*SEQ + s + i)*DH + d] = f2bf(v4[i]);
      }
    });
}

// ---------------- rel: C = Q_all @ E^T, banded epilogue -> relS[bh*920+q][k] ----------------
__global__ __launch_bounds__(512) void k_rel(const unsigned short* __restrict__ Qb,
                                             const unsigned short* __restrict__ E,
                                             unsigned short* __restrict__ relS){
  int m0 = blockIdx.x * 192, n0 = blockIdx.y * 192;
  int s0 = m0 % SEQ;
  int qlo = s0, qhi = s0 + 191;
  if(qhi >= SEQ){ qlo = 0; qhi = SEQ - 1; }
  if(n0 + 191 < 919 - qhi || n0 > 1838 - qlo) return;
  gemm192(Qb, DH, NBH*SEQ, E, DH, NREL, DH, m0, n0,
    [=] __device__ (int m, int n, f32x4 v4){
      #pragma unroll
      for(int i = 0; i < 4; i++){
        int mi = m + i;
        if(mi >= NBH*SEQ) continue;
        int q = mi % SEQ;
        int j = n - 919 + q;
        if(j < 0 || j >= SEQ) continue;
        relS[(size_t)mi*SEQ + j] = f2bf(v4[i]);
      }
    });
}

// ---------------- S-GEMM: per-bh S = Q K^T; in-place epilogue P = exp(S + relS) ----------------
__global__ __launch_bounds__(512) void k_sgemm(const unsigned short* __restrict__ Qb,
                                               const unsigned short* __restrict__ Kb,
                                               unsigned short* __restrict__ P){
  int id = blockIdx.x;                        // 400 blocks
  int idp = (id & 7) * 50 + (id >> 3);        // XCD-contiguous: 2 bh per XCD
  int bh = idp / 25, r = idp % 25;
  int m0 = (r % 5) * 192, n0 = (r / 5) * 192;
  const unsigned short* A = Qb + (size_t)bh*SEQ*DH;
  const unsigned short* B = Kb + (size_t)bh*SEQ*DH;
  unsigned short* Pbh = P + (size_t)bh*SEQ*SEQ;
  gemm192(A, DH, SEQ, B, DH, SEQ, DH, m0, n0,
    [=] __device__ (int m, int n, f32x4 v4){
      if(n >= SEQ) return;
      #pragma unroll
      for(int i = 0; i < 4; i++){
        int mi = m + i;
        if(mi >= SEQ) continue;
        size_t off = (size_t)mi*SEQ + n;
        float p = __expf(v4[i] + bf2f(Pbh[off]));   // same-thread read-then-write: no race
        Pbh[off] = f2bf(p);
      }
    });
}

// ---------------- row sums of P (f32) ----------------
__global__ __launch_bounds__(256) void k_rowsum(const unsigned short* __restrict__ P,
                                                float* __restrict__ rs){
  int w = threadIdx.x >> 6, l = threadIdx.x & 63;
  #pragma unroll
  for(int r = 0; r < 4; r++){
    int row = blockIdx.x * 16 + w * 4 + r;
    size_t base = (size_t)row * SEQ;
    float s = 0.f;
    for(int c = l; c < 115; c += 64){           // 115*8 == 920
      u16x8 v = *(const u16x8*)(P + base + (size_t)c*8);
      #pragma unroll
      for(int j = 0; j < 8; j++) s += bf2f(v[j]);
    }
    s += __shfl_xor(s, 1);  s += __shfl_xor(s, 2);  s += __shfl_xor(s, 4);
    s += __shfl_xor(s, 8);  s += __shfl_xor(s, 16); s += __shfl_xor(s, 32);
    if(l == 0) rs[row] = s;
  }
}

// ---------------- PV: per-bh ctx = P V (K=920, tail-masked), scale by 1/rowsum -> out ----------------
__global__ __launch_bounds__(512) void k_pv(const unsigned short* __restrict__ P,
                                            const unsigned short* __restrict__ Vt,
                                            const float* __restrict__ rs,
                                            float* __restrict__ out){
  int id = blockIdx.x;                        // 160 blocks
  int idp = (id & 7) * 20 + (id >> 3);        // 2 bh per XCD
  int bh = idp / 10, r = idp % 10;
  int m0 = (r % 5) * 192, n0 = (r / 5) * 192;
  const unsigned short* A = P  + (size_t)bh*SEQ*SEQ;
  const unsigned short* B = Vt + (size_t)bh*DH*SEQ;
  const float* rsb = rs + (size_t)bh*SEQ;
  const int b = bh >> 2, h = bh & 3;
  gemm192(A, SEQ, SEQ, B, SEQ, DH, SEQ, m0, n0,
    [=] __device__ (int m, int n, f32x4 v4){
      #pragma unroll
      for(int i = 0; i < 4; i++){
        int mi = m + i;
        if(mi >= SEQ) continue;
        out[((size_t)(b*SEQ + mi))*DM + h*DH + n] = v4[i] / rsb[mi];
      }
    });
}

extern "C" void kernel_launch(void* const* d_in, const int* in_sizes, int n_in,
                              void* d_out, int out_size, void* d_ws, size_t ws_size,
                              hipStream_t stream){
  const float* X  = (const float*)d_in[0];
  const float* qw = (const float*)d_in[1];
  const float* kw = (const float*)d_in[2];
  const float* vw = (const float*)d_in[3];
  const float* de = (const float*)d_in[4];
  float* out = (float*)d_out;
  char* ws = (char*)d_ws;

  // ws layout (bytes), total 62,412,032:
  // [0, 11304960)           Qb  bf16 (bh,s,d)   -> reused as rowsum (f32, 58KB) after k_sgemm
  // [11304960, 22609920)    Kb  bf16 (bh,s,d)
  // [22609920, 33914880)    Vt  bf16 (bh,d,s)
  // [33914880, 60999680)    relS bf16 [14720][920]  (== P in place after k_sgemm)
  //                         (aliased before k_rel: Xb at 33914880, Wt at 45219840)
  // [60999680, 62412032)    Eb  bf16 (1839x384)  -- placed last so relS row-overreads stay in ws
  unsigned short* Qb   = (unsigned short*)ws;
  unsigned short* Kb   = (unsigned short*)(ws + 11304960);
  unsigned short* Vt   = (unsigned short*)(ws + 22609920);
  unsigned short* relS = (unsigned short*)(ws + 33914880);
  unsigned short* Eb   = (unsigned short*)(ws + 60999680);
  unsigned short* Xb   = (unsigned short*)(ws + 33914880);
  unsigned short* Wt   = (unsigned short*)(ws + 45219840);
  float*          rsum = (float*)ws;          // aliases Qb (dead by then)

  k_f2bf<<<dim3(2048), dim3(256), 0, stream>>>(X,  Xb, MTOK*DM);
  k_f2bf<<<dim3(690),  dim3(256), 0, stream>>>(de, Eb, NREL*DH);
  k_wt3<<<dim3(48,48,3), dim3(32,8), 0, stream>>>(qw, kw, vw, Wt);
  k_proj<<<dim3(480), dim3(512), 0, stream>>>(Xb, Wt, Qb, Kb, Vt);
  k_rel<<<dim3(77,10), dim3(512), 0, stream>>>(Qb, Eb, relS);     // overwrites Xb/Wt (dead)
  k_sgemm<<<dim3(400), dim3(512), 0, stream>>>(Qb, Kb, relS);     // relS -> P in place
  k_rowsum<<<dim3(920), dim3(256), 0, stream>>>(relS, rsum);
  k_pv<<<dim3(160), dim3(512), 0, stream>>>(relS, Vt, rsum, out);
}

// Round 6
// 219.661 us; speedup vs baseline: 1.1688x; 1.0513x over previous
//
#include <hip/hip_runtime.h>
#include <cstdint>
#include <cstddef>

// ---- problem constants ----
#define SEQ   920
#define DM    1536
#define DH    384
#define NHD   4
#define NB    4
#define NBH   16          // NB*NHD
#define MTOK  3680        // NB*SEQ
#define NREL  1839        // 2*920-1

typedef short          bf16x8 __attribute__((ext_vector_type(8)));
typedef float          f32x4  __attribute__((ext_vector_type(4)));
typedef unsigned short u16x4  __attribute__((ext_vector_type(4)));
typedef unsigned short u16x8  __attribute__((ext_vector_type(8)));

__device__ __forceinline__ unsigned short f2bf(float f){
  union{float f; unsigned u;} v; v.f = f;
  unsigned r = v.u + 0x7FFFu + ((v.u >> 16) & 1u);
  return (unsigned short)(r >> 16);
}
__device__ __forceinline__ float bf2f(unsigned short h){
  union{unsigned u; float f;} v; v.u = ((unsigned)h) << 16;
  return v.f;
}
__device__ __forceinline__ f32x4 mfma_bf16(bf16x8 a, bf16x8 b, f32x4 c){
  return __builtin_amdgcn_mfma_f32_16x16x32_bf16(a, b, c, 0, 0, 0);
}
__device__ __forceinline__ void gload_lds16(const void* g, void* l){
  __builtin_amdgcn_global_load_lds((const __attribute__((address_space(1))) void*)g,
                                   (__attribute__((address_space(3))) void*)l, 16, 0, 0);
}

// ---------------- convert f32 -> bf16 (n % 4 == 0) ----------------
__global__ __launch_bounds__(256) void k_f2bf(const float* __restrict__ src,
                                              unsigned short* __restrict__ dst, int n){
  int i = (blockIdx.x * 256 + threadIdx.x) * 4;
  int stride = gridDim.x * 256 * 4;
  for(; i + 3 < n; i += stride){
    f32x4 v = *(const f32x4*)(src + i);
    u16x4 o; o.x = f2bf(v.x); o.y = f2bf(v.y); o.z = f2bf(v.z); o.w = f2bf(v.w);
    *(u16x4*)(dst + i) = o;
  }
}

// ---- transpose+convert all 3 weights: W[k][n] f32 -> Wt[z*1536+n][k] bf16 (z = blockIdx.z) ----
__global__ __launch_bounds__(256) void k_wt3(const float* __restrict__ qw,
                                             const float* __restrict__ kw,
                                             const float* __restrict__ vw,
                                             unsigned short* __restrict__ wt){
  __shared__ float t[32][33];
  const float* w = blockIdx.z == 0 ? qw : (blockIdx.z == 1 ? kw : vw);
  int k0 = blockIdx.x * 32, n0 = blockIdx.y * 32;
  int tx = threadIdx.x, ty = threadIdx.y;       // (32,8)
  #pragma unroll
  for(int j = 0; j < 4; j++)
    t[ty*4+j][tx] = w[(size_t)(k0 + ty*4 + j) * DM + n0 + tx];
  __syncthreads();
  #pragma unroll
  for(int j = 0; j < 4; j++)
    wt[(size_t)(blockIdx.z*DM + n0 + ty*4 + j) * DM + k0 + tx] = f2bf(t[tx][ty*4+j]);
}

// ====== 192x192 tile, BK=64, 8-wave, ring-3, counted-vmcnt, 3-PHASE interleaved GEMM ======
// B given as B^T (n-major, ldb = K elements). K not nec. multiple of 64: last 128B k-chunk
// masked on the A side (valid bytes tb), so B-side garbage multiplies zero. Row overreads
// (<=80B past last row) must land in mapped memory — ws layout guarantees this.
// Schedule per K-step (slot st holds tile t, confirmed landed by prev iter's vmcnt+barrier):
//   P1: ds_read B(6)+A01(4) | stage pair0 of tile t+2 | bar | lgkm0 | 12 MFMA | bar
//   P2: ds_read A23(4)      | stage pair1             | bar | lgkm0 | 12 MFMA | bar
//   P3: ds_read A45(4)      | stage pair2 + vmcnt(6)  | bar | lgkm0 | 12 MFMA | bar
// vmcnt(6) at P3 = tile t+2's 6 loads remain in flight => tile t+1 landed for next iter.
template<class Epi>
__device__ __forceinline__ void gemm192(const unsigned short* __restrict__ A, int lda, int Amax,
                                        const unsigned short* __restrict__ B, int ldb, int Bmax,
                                        int K, int m0, int n0, Epi epi){
  __shared__ unsigned short As[3*192*64];   // 3 slots x 24KB, rows 128B, XOR-swizzled content
  __shared__ unsigned short Bs[3*192*64];
  const int tid = threadIdx.x;
  const int w = tid >> 6, l = tid & 63;
  const int lg = l >> 4, lo = l & 15;
  const int wm = w >> 2, wn = w & 3;        // wave grid 2(M) x 4(N); per-wave 96x48

  const char* ga[3]; const char* gb[3];
  #pragma unroll
  for(int r = 0; r < 3; r++){
    int row = r*64 + (tid >> 3);
    int gslot = (tid & 7) ^ (row & 7);
    int ar = m0 + row; ar = ar < Amax ? ar : Amax - 1;
    ga[r] = (const char*)A + (size_t)ar*lda*2 + gslot*16;
    int br = n0 + row; br = br < Bmax ? br : Bmax - 1;
    gb[r] = (const char*)B + (size_t)br*ldb*2 + gslot*16;
  }
  const int ldst = tid * 16;

  auto stage_pair = [&](int kt, int slot, int r){   // one A + one B 16B load ("pair")
    size_t koff = (size_t)kt * 128;                 // 64 cols * 2B
    gload_lds16(ga[r] + koff, (char*)As + slot*24576 + r*8192 + ldst);
    gload_lds16(gb[r] + koff, (char*)Bs + slot*24576 + r*8192 + ldst);
  };

  f32x4 acc[6][3] = {};
  const int sw = (lo & 7) << 4;
  const int nk = (2*K + 127) >> 7;
  const int tb = 2*K - (nk - 1)*128;        // valid bytes in last k-chunk (128 if K%64==0)
  const bool keep0 = (lg*16) < tb;
  const bool keep1 = (64 + lg*16) < tb;

  // prologue: tiles 0,1 in flight; confirm tile 0 landed
  #pragma unroll
  for(int r = 0; r < 3; r++) stage_pair(0, 0, r);
  #pragma unroll
  for(int r = 0; r < 3; r++) stage_pair(1, 1, r);
  asm volatile("s_waitcnt vmcnt(6)" ::: "memory");
  __builtin_amdgcn_s_barrier();

  int st = 0;
  for(int t = 0; t < nk; t++){
    const bool last = (t == nk - 1);
    const bool pf = (t + 2 < nk);
    const int s2 = st + 2 >= 3 ? st - 1 : st + 2;
    const char* Ab = (const char*)As + st*24576;
    const char* Bb = (const char*)Bs + st*24576;

    bf16x8 bfr[3][2], afr[2][2];

    // ---------------- phase 1: all B frags + A frags 0..1 ----------------
    #pragma unroll
    for(int fj = 0; fj < 3; fj++){
      int row = wn*48 + fj*16 + lo;
      #pragma unroll
      for(int kk = 0; kk < 2; kk++)
        bfr[fj][kk] = *(const bf16x8*)(Bb + row*128 + ((kk*64 + lg*16) ^ sw));
    }
    #pragma unroll
    for(int fi = 0; fi < 2; fi++){
      int row = wm*96 + fi*16 + lo;
      #pragma unroll
      for(int kk = 0; kk < 2; kk++)
        afr[fi][kk] = *(const bf16x8*)(Ab + row*128 + ((kk*64 + lg*16) ^ sw));
    }
    if(pf) stage_pair(t + 2, s2, 0);
    if(last){
      #pragma unroll
      for(int fi = 0; fi < 2; fi++){
        if(!keep0) afr[fi][0] = bf16x8{};
        if(!keep1) afr[fi][1] = bf16x8{};
      }
    }
    __builtin_amdgcn_s_barrier();
    asm volatile("s_waitcnt lgkmcnt(0)" ::: "memory");
    __builtin_amdgcn_s_setprio(1);
    #pragma unroll
    for(int kk = 0; kk < 2; kk++)
      #pragma unroll
      for(int fi = 0; fi < 2; fi++)
        #pragma unroll
        for(int fj = 0; fj < 3; fj++)
          acc[fi][fj] = mfma_bf16(afr[fi][kk], bfr[fj][kk], acc[fi][fj]);
    __builtin_amdgcn_s_setprio(0);
    __builtin_amdgcn_s_barrier();

    // ---------------- phase 2: A frags 2..3 ----------------
    #pragma unroll
    for(int fi = 0; fi < 2; fi++){
      int row = wm*96 + (fi + 2)*16 + lo;
      #pragma unroll
      for(int kk = 0; kk < 2; kk++)
        afr[fi][kk] = *(const bf16x8*)(Ab + row*128 + ((kk*64 + lg*16) ^ sw));
    }
    if(pf) stage_pair(t + 2, s2, 1);
    if(last){
      #pragma unroll
      for(int fi = 0; fi < 2; fi++){
        if(!keep0) afr[fi][0] = bf16x8{};
        if(!keep1) afr[fi][1] = bf16x8{};
      }
    }
    __builtin_amdgcn_s_barrier();
    asm volatile("s_waitcnt lgkmcnt(0)" ::: "memory");
    __builtin_amdgcn_s_setprio(1);
    #pragma unroll
    for(int kk = 0; kk < 2; kk++)
      #pragma unroll
      for(int fi = 0; fi < 2; fi++)
        #pragma unroll
        for(int fj = 0; fj < 3; fj++)
          acc[fi + 2][fj] = mfma_bf16(afr[fi][kk], bfr[fj][kk], acc[fi + 2][fj]);
    __builtin_amdgcn_s_setprio(0);
    __builtin_amdgcn_s_barrier();

    // ---------------- phase 3: A frags 4..5 + end-of-iter readiness vmcnt ----------------
    #pragma unroll
    for(int fi = 0; fi < 2; fi++){
      int row = wm*96 + (fi + 4)*16 + lo;
      #pragma unroll
      for(int kk = 0; kk < 2; kk++)
        afr[fi][kk] = *(const bf16x8*)(Ab + row*128 + ((kk*64 + lg*16) ^ sw));
    }
    if(pf){
      stage_pair(t + 2, s2, 2);
      asm volatile("s_waitcnt vmcnt(6)" ::: "memory");   // tile t+1 landed; t+2 in flight
    } else if(t + 1 < nk){
      asm volatile("s_waitcnt vmcnt(0)" ::: "memory");   // drain: tile t+1 landed
    }
    if(last){
      #pragma unroll
      for(int fi = 0; fi < 2; fi++){
        if(!keep0) afr[fi][0] = bf16x8{};
        if(!keep1) afr[fi][1] = bf16x8{};
      }
    }
    __builtin_amdgcn_s_barrier();
    asm volatile("s_waitcnt lgkmcnt(0)" ::: "memory");
    __builtin_amdgcn_s_setprio(1);
    #pragma unroll
    for(int kk = 0; kk < 2; kk++)
      #pragma unroll
      for(int fi = 0; fi < 2; fi++)
        #pragma unroll
        for(int fj = 0; fj < 3; fj++)
          acc[fi + 4][fj] = mfma_bf16(afr[fi][kk], bfr[fj][kk], acc[fi + 4][fj]);
    __builtin_amdgcn_s_setprio(0);
    __builtin_amdgcn_s_barrier();

    st = st + 1 >= 3 ? 0 : st + 1;
  }

  #pragma unroll
  for(int fi = 0; fi < 6; fi++)
    #pragma unroll
    for(int fj = 0; fj < 3; fj++){
      int m = m0 + wm*96 + fi*16 + lg*4;
      int n = n0 + wn*48 + fj*16 + lo;
      epi(m, n, acc[fi][fj]);
    }
}

// ---------------- projection: C = X @ [qw kw vw] -> Qb/Kb (bh,s,d), Vt (bh,d,s) ----------------
__global__ __launch_bounds__(512) void k_proj(const unsigned short* __restrict__ X,
                                              const unsigned short* __restrict__ Wt,
                                              unsigned short* __restrict__ Qb,
                                              unsigned short* __restrict__ Kb,
                                              unsigned short* __restrict__ Vt){
  int bid = blockIdx.x;                       // 480 blocks, 480 % 8 == 0
  int wg  = (bid & 7) * 60 + (bid >> 3);      // XCD-contiguous chunks
  int m0 = (wg % 20) * 192, n0 = (wg / 20) * 192;
  gemm192(X, DM, MTOK, Wt, DM, 3*DM, DM, m0, n0,
    [=] __device__ (int m, int n, f32x4 v4){
      if(m >= MTOK) return;                   // 4-row group fully in/out (both %4==0)
      int which = n / DM, r = n % DM, h = r / DH, d = r % DH;
      int b = m / SEQ, s = m % SEQ;           // 920%4==0 -> group stays in one b
      int bh = b * NHD + h;
      if(which == 2){
        u16x4 o;
        o.x = f2bf(v4.x); o.y = f2bf(v4.y); o.z = f2bf(v4.z); o.w = f2bf(v4.w);
        *(u16x4*)(Vt + ((size_t)bh*DH + d)*SEQ + s) = o;
      } else if(which == 0){
        #pragma unroll
        for(int i = 0; i < 4; i++)
          Qb[((size_t)bh*SEQ + s + i)*DH + d] = f2bf(v4[i] * 0.05103103630798287f);
      } else {
        #pragma unroll
        for(int i = 0; i < 4; i++)
          Kb[((size_t)bh*SEQ + s + i)*DH + d] = f2bf(v4[i]);
      }
    });
}

// ---------------- rel: C = Q_all @ E^T, banded epilogue -> relS[bh*920+q][k] ----------------
__global__ __launch_bounds__(512) void k_rel(const unsigned short* __restrict__ Qb,
                                             const unsigned short* __restrict__ E,
                                             unsigned short* __restrict__ relS){
  int m0 = blockIdx.x * 192, n0 = blockIdx.y * 192;
  int s0 = m0 % SEQ;
  int qlo = s0, qhi = s0 + 191;
  if(qhi >= SEQ){ qlo = 0; qhi = SEQ - 1; }
  if(n0 + 191 < 919 - qhi || n0 > 1838 - qlo) return;
  gemm192(Qb, DH, NBH*SEQ, E, DH, NREL, DH, m0, n0,
    [=] __device__ (int m, int n, f32x4 v4){
      #pragma unroll
      for(int i = 0; i < 4; i++){
        int mi = m + i;
        if(mi >= NBH*SEQ) continue;
        int q = mi % SEQ;
        int j = n - 919 + q;
        if(j < 0 || j >= SEQ) continue;
        relS[(size_t)mi*SEQ + j] = f2bf(v4[i]);
      }
    });
}

// ---------------- S-GEMM: per-bh S = Q K^T; in-place epilogue P = exp(S + relS) ----------------
__global__ __launch_bounds__(512) void k_sgemm(const unsigned short* __restrict__ Qb,
                                               const unsigned short* __restrict__ Kb,
                                               unsigned short* __restrict__ P){
  int id = blockIdx.x;                        // 400 blocks
  int idp = (id & 7) * 50 + (id >> 3);        // XCD-contiguous: 2 bh per XCD
  int bh = idp / 25, r = idp % 25;
  int m0 = (r % 5) * 192, n0 = (r / 5) * 192;
  const unsigned short* A = Qb + (size_t)bh*SEQ*DH;
  const unsigned short* B = Kb + (size_t)bh*SEQ*DH;
  unsigned short* Pbh = P + (size_t)bh*SEQ*SEQ;
  gemm192(A, DH, SEQ, B, DH, SEQ, DH, m0, n0,
    [=] __device__ (int m, int n, f32x4 v4){
      if(n >= SEQ) return;
      #pragma unroll
      for(int i = 0; i < 4; i++){
        int mi = m + i;
        if(mi >= SEQ) continue;
        size_t off = (size_t)mi*SEQ + n;
        float p = __expf(v4[i] + bf2f(Pbh[off]));   // same-thread read-then-write: no race
        Pbh[off] = f2bf(p);
      }
    });
}

// ---------------- row sums of P (f32) ----------------
__global__ __launch_bounds__(256) void k_rowsum(const unsigned short* __restrict__ P,
                                                float* __restrict__ rs){
  int w = threadIdx.x >> 6, l = threadIdx.x & 63;
  #pragma unroll
  for(int r = 0; r < 4; r++){
    int row = blockIdx.x * 16 + w * 4 + r;
    size_t base = (size_t)row * SEQ;
    float s = 0.f;
    for(int c = l; c < 115; c += 64){           // 115*8 == 920
      u16x8 v = *(const u16x8*)(P + base + (size_t)c*8);
      #pragma unroll
      for(int j = 0; j < 8; j++) s += bf2f(v[j]);
    }
    s += __shfl_xor(s, 1);  s += __shfl_xor(s, 2);  s += __shfl_xor(s, 4);
    s += __shfl_xor(s, 8);  s += __shfl_xor(s, 16); s += __shfl_xor(s, 32);
    if(l == 0) rs[row] = s;
  }
}

// ---------------- PV: per-bh ctx = P V (K=920, tail-masked), scale by 1/rowsum -> out ----------------
__global__ __launch_bounds__(512) void k_pv(const unsigned short* __restrict__ P,
                                            const unsigned short* __restrict__ Vt,
                                            const float* __restrict__ rs,
                                            float* __restrict__ out){
  int id = blockIdx.x;                        // 160 blocks
  int idp = (id & 7) * 20 + (id >> 3);        // 2 bh per XCD
  int bh = idp / 10, r = idp % 10;
  int m0 = (r % 5) * 192, n0 = (r / 5) * 192;
  const unsigned short* A = P  + (size_t)bh*SEQ*SEQ;
  const unsigned short* B = Vt + (size_t)bh*DH*SEQ;
  const float* rsb = rs + (size_t)bh*SEQ;
  const int b = bh >> 2, h = bh & 3;
  gemm192(A, SEQ, SEQ, B, SEQ, DH, SEQ, m0, n0,
    [=] __device__ (int m, int n, f32x4 v4){
      #pragma unroll
      for(int i = 0; i < 4; i++){
        int mi = m + i;
        if(mi >= SEQ) continue;
        out[((size_t)(b*SEQ + mi))*DM + h*DH + n] = v4[i] / rsb[mi];
      }
    });
}

extern "C" void kernel_launch(void* const* d_in, const int* in_sizes, int n_in,
                              void* d_out, int out_size, void* d_ws, size_t ws_size,
                              hipStream_t stream){
  const float* X  = (const float*)d_in[0];
  const float* qw = (const float*)d_in[1];
  const float* kw = (const float*)d_in[2];
  const float* vw = (const float*)d_in[3];
  const float* de = (const float*)d_in[4];
  float* out = (float*)d_out;
  char* ws = (char*)d_ws;

  // ws layout (bytes), total 62,412,032:
  // [0, 11304960)           Qb  bf16 (bh,s,d)   -> reused as rowsum (f32, 58KB) after k_sgemm
  // [11304960, 22609920)    Kb  bf16 (bh,s,d)
  // [22609920, 33914880)    Vt  bf16 (bh,d,s)
  // [33914880, 60999680)    relS bf16 [14720][920]  (== P in place after k_sgemm)
  //                         (aliased before k_rel: Xb at 33914880, Wt at 45219840)
  // [60999680, 62412032)    Eb  bf16 (1839x384)  -- placed last so relS row-overreads stay in ws
  unsigned short* Qb   = (unsigned short*)ws;
  unsigned short* Kb   = (unsigned short*)(ws + 11304960);
  unsigned short* Vt   = (unsigned short*)(ws + 22609920);
  unsigned short* relS = (unsigned short*)(ws + 33914880);
  unsigned short* Eb   = (unsigned short*)(ws + 60999680);
  unsigned short* Xb   = (unsigned short*)(ws + 33914880);
  unsigned short* Wt   = (unsigned short*)(ws + 45219840);
  float*          rsum = (float*)ws;          // aliases Qb (dead by then)

  k_f2bf<<<dim3(2048), dim3(256), 0, stream>>>(X,  Xb, MTOK*DM);
  k_f2bf<<<dim3(690),  dim3(256), 0, stream>>>(de, Eb, NREL*DH);
  k_wt3<<<dim3(48,48,3), dim3(32,8), 0, stream>>>(qw, kw, vw, Wt);
  k_proj<<<dim3(480), dim3(512), 0, stream>>>(Xb, Wt, Qb, Kb, Vt);
  k_rel<<<dim3(77,10), dim3(512), 0, stream>>>(Qb, Eb, relS);     // overwrites Xb/Wt (dead)
  k_sgemm<<<dim3(400), dim3(512), 0, stream>>>(Qb, Kb, relS);     // relS -> P in place
  k_rowsum<<<dim3(920), dim3(256), 0, stream>>>(relS, rsum);
  k_pv<<<dim3(160), dim3(512), 0, stream>>>(relS, Vt, rsum, out);
}